// Round 8
// baseline (358.157 us; speedup 1.0000x reference)
//
#include <hip/hip_runtime.h>

// GRU: H=32, I=1, B=2048, T=1024, fused output Linear(32,1).
// Mapping: 1 batch per 64-lane wave (2048 waves = 2/SIMD). Lane (half, j)
// owns gate rows {r,z,n} of unit j for K-range [16*half, 16*half+16).
// v8: the entire 32-step inner loop is ONE asm volatile block. Rounds 3-7
// showed the compiler parking loop-invariants in AGPRs and shuttling
// (VGPR_Count 40-52 < operand count; ~2x VALU bloat, v_accvgpr_read per
// use). Operands bound "v" across the whole block stay in real VGPRs for
// all 32 steps; temporaries live in fixed clobbered regs so ds_read_b128
// destinations are aligned quads sliceable per-dword for v_dot2_f32_f16.
// Per step: 7 DS ops (b16 h-publish, 2x b128 broadcast read, 3 bpermute
// K-half combine, 1 y-stash write), 24 dot2 + ~23 scalar VALU, 3 SALU.

constexpr int H  = 32;
constexpr int TT = 1024;
constexpr int BB = 2048;

typedef _Float16 hf2 __attribute__((ext_vector_type(2)));

__device__ __forceinline__ unsigned pack2(float a, float b) {
    hf2 t; t.x = (_Float16)a; t.y = (_Float16)b;
    return __builtin_bit_cast(unsigned, t);
}

__global__ __launch_bounds__(256, 2)
void gru_fused(const float* __restrict__ x,      // [B,T]
               const float* __restrict__ h0,     // [1,B,H]
               const float* __restrict__ W_ih,   // [3H,1]
               const float* __restrict__ W_hh,   // [3H,H]
               const float* __restrict__ b_ih,   // [3H]
               const float* __restrict__ b_hh,   // [3H]
               const float* __restrict__ W_out,  // [1,H]
               const float* __restrict__ b_out,  // [1]
               float* __restrict__ out)          // y[B,T] ++ h_n[B,H]
{
    __shared__ __align__(16) _Float16 hbuf[4][32];   // [wave][h as f16]
    __shared__ float ybuf[4][33 * 32];               // y transpose, 33-stride

    const int tid  = threadIdx.x;
    const int w    = tid >> 6;
    const int lane = tid & 63;
    const int half = lane >> 5;
    const int j    = lane & 31;
    const int b    = (blockIdx.x << 2) | w;

    const float NL2E = -1.44269504f;   // -log2(e): folded into r,z weights
    const float P2L2 =  2.88539008f;   //  2*log2(e): folded into n weights

    // --- weights: own K-half of rows {j, H+j, 2H+j}, pre-scaled, f16 pairs ---
    const float* Wrp = &W_hh[(0 * H + j) * H + 16 * half];
    const float* Wzp = &W_hh[(1 * H + j) * H + 16 * half];
    const float* Wnp = &W_hh[(2 * H + j) * H + 16 * half];
    unsigned wr[8], wz[8], wn[8];
#pragma unroll
    for (int k = 0; k < 8; ++k) {
        wr[k] = pack2(Wrp[2 * k] * NL2E, Wrp[2 * k + 1] * NL2E);
        wz[k] = pack2(Wzp[2 * k] * NL2E, Wzp[2 * k + 1] * NL2E);
        wn[k] = pack2(Wnp[2 * k] * P2L2, Wnp[2 * k + 1] * P2L2);
    }
    // bias / input-weight terms enter accumulators once (zero on half1)
    const float wir = half ? 0.0f : (W_ih[j] * NL2E);
    const float wiz = half ? 0.0f : (W_ih[H + j] * NL2E);
    const float br  = half ? 0.0f : ((b_ih[j] + b_hh[j]) * NL2E);
    const float bz  = half ? 0.0f : ((b_ih[H + j] + b_hh[H + j]) * NL2E);
    const float bhn = half ? 0.0f : (b_hh[2 * H + j] * P2L2);
    const float win = W_ih[2 * H + j] * P2L2;
    const float bin = b_ih[2 * H + j] * P2L2;
    const float wo  = W_out[j];
    const float bo  = b_out[0];

    float h = h0[b * H + j];

    const float* xb = x + (size_t)b * TT;
    float*       yb = out + (size_t)b * TT;

    // LDS raw offsets (lo32 of generic pointer to LDS object == DS address)
    const unsigned ha = (unsigned)(size_t)&hbuf[w][j];            // h publish (both halves same addr)
    const unsigned hr = (unsigned)(size_t)&hbuf[w][16 * half];    // own K-half, 16B-aligned
    const unsigned ya = (unsigned)(size_t)&ybuf[w][j];            // y stash base
    const int      bp = (lane ^ 32) << 2;                         // bpermute addr (xor-32)
    float* yrow = &ybuf[w][0];

#pragma unroll 1
    for (int t0 = 0; t0 < TT; t0 += 32) {
        const float xv = xb[t0 + j];   // lane j holds x[t0+j] (both halves)

        asm volatile(
            "s_mov_b32 s20, 0\n\t"
            "v_mov_b32 v82, %[ya]\n\t"
            "L_gru_%=:\n\t"
            "v_cvt_f16_f32 v33, %[h]\n\t"
            "ds_write_b16 %[ha], v33\n\t"
            "ds_read_b128 v[36:39], %[hr]\n\t"
            "ds_read_b128 v[40:43], %[hr] offset:16\n\t"
            "v_readlane_b32 s21, %[xv], s20\n\t"
            "s_waitcnt lgkmcnt(0)\n\t"
            "v_dot2_f32_f16 v68, %[r0], v36, %[br]\n\t"
            "v_dot2_f32_f16 v69, %[z0], v36, %[bz]\n\t"
            "v_dot2_f32_f16 v70, %[n0], v36, %[bn]\n\t"
            "v_dot2_f32_f16 v68, %[r1], v37, v68\n\t"
            "v_dot2_f32_f16 v69, %[z1], v37, v69\n\t"
            "v_dot2_f32_f16 v70, %[n1], v37, v70\n\t"
            "v_dot2_f32_f16 v68, %[r2], v38, v68\n\t"
            "v_dot2_f32_f16 v69, %[z2], v38, v69\n\t"
            "v_dot2_f32_f16 v70, %[n2], v38, v70\n\t"
            "v_dot2_f32_f16 v68, %[r3], v39, v68\n\t"
            "v_dot2_f32_f16 v69, %[z3], v39, v69\n\t"
            "v_dot2_f32_f16 v70, %[n3], v39, v70\n\t"
            "v_dot2_f32_f16 v68, %[r4], v40, v68\n\t"
            "v_dot2_f32_f16 v69, %[z4], v40, v69\n\t"
            "v_dot2_f32_f16 v70, %[n4], v40, v70\n\t"
            "v_dot2_f32_f16 v68, %[r5], v41, v68\n\t"
            "v_dot2_f32_f16 v69, %[z5], v41, v69\n\t"
            "v_dot2_f32_f16 v70, %[n5], v41, v70\n\t"
            "v_dot2_f32_f16 v68, %[r6], v42, v68\n\t"
            "v_dot2_f32_f16 v69, %[z6], v42, v69\n\t"
            "v_dot2_f32_f16 v70, %[n6], v42, v70\n\t"
            "v_dot2_f32_f16 v68, %[r7], v43, v68\n\t"
            "v_dot2_f32_f16 v69, %[z7], v43, v69\n\t"
            "v_dot2_f32_f16 v70, %[n7], v43, v70\n\t"
            "v_fmac_f32 v68, s21, %[wir]\n\t"
            "v_fmac_f32 v69, s21, %[wiz]\n\t"
            "ds_bpermute_b32 v93, %[bp], v68\n\t"
            "ds_bpermute_b32 v94, %[bp], v69\n\t"
            "ds_bpermute_b32 v95, %[bp], v70\n\t"
            "s_waitcnt lgkmcnt(0)\n\t"
            "v_add_f32 v68, v68, v93\n\t"
            "v_add_f32 v69, v69, v94\n\t"
            "v_add_f32 v70, v70, v95\n\t"
            "v_exp_f32 v71, v68\n\t"
            "v_exp_f32 v72, v69\n\t"
            "s_nop 1\n\t"
            "v_add_f32 v71, 1.0, v71\n\t"
            "v_add_f32 v72, 1.0, v72\n\t"
            "v_rcp_f32 v71, v71\n\t"
            "v_rcp_f32 v72, v72\n\t"
            "v_fma_f32 v74, s21, %[wi], %[bi]\n\t"
            "s_nop 0\n\t"
            "v_fmac_f32 v74, v71, v70\n\t"
            "v_exp_f32 v75, v74\n\t"
            "s_nop 1\n\t"
            "v_add_f32 v75, 1.0, v75\n\t"
            "v_rcp_f32 v75, v75\n\t"
            "s_nop 1\n\t"
            "v_fma_f32 v76, -2.0, v75, 1.0\n\t"
            "v_sub_f32 v77, %[h], v76\n\t"
            "v_fma_f32 %[h], v72, v77, v76\n\t"
            "v_mul_f32 v78, %[wo], %[h]\n\t"
            "ds_write_b32 v82, v78\n\t"
            "v_add_u32 v82, 132, v82\n\t"
            "s_add_i32 s20, s20, 1\n\t"
            "s_cmp_lt_u32 s20, 32\n\t"
            "s_cbranch_scc1 L_gru_%=\n\t"
            "s_waitcnt lgkmcnt(0)"
            : [h]"+v"(h)
            : [xv]"v"(xv), [ha]"v"(ha), [hr]"v"(hr), [bp]"v"(bp), [ya]"v"(ya),
              [wir]"v"(wir), [wiz]"v"(wiz), [wi]"v"(win), [bi]"v"(bin),
              [wo]"v"(wo), [br]"v"(br), [bz]"v"(bz), [bn]"v"(bhn),
              [r0]"v"(wr[0]), [r1]"v"(wr[1]), [r2]"v"(wr[2]), [r3]"v"(wr[3]),
              [r4]"v"(wr[4]), [r5]"v"(wr[5]), [r6]"v"(wr[6]), [r7]"v"(wr[7]),
              [z0]"v"(wz[0]), [z1]"v"(wz[1]), [z2]"v"(wz[2]), [z3]"v"(wz[3]),
              [z4]"v"(wz[4]), [z5]"v"(wz[5]), [z6]"v"(wz[6]), [z7]"v"(wz[7]),
              [n0]"v"(wn[0]), [n1]"v"(wn[1]), [n2]"v"(wn[2]), [n3]"v"(wn[3]),
              [n4]"v"(wn[4]), [n5]"v"(wn[5]), [n6]"v"(wn[6]), [n7]"v"(wn[7])
            : "memory", "scc", "s20", "s21",
              "v33", "v36", "v37", "v38", "v39", "v40", "v41", "v42", "v43",
              "v68", "v69", "v70", "v71", "v72", "v74", "v75", "v76", "v77",
              "v78", "v82", "v93", "v94", "v95");

        // amortized y reduction: lane (half,j) sums row j (broadcast across halves)
        float s0 = 0.0f, s1 = 0.0f, s2 = 0.0f, s3 = 0.0f;
#pragma unroll
        for (int k = 0; k < 32; k += 4) {
            s0 += yrow[33 * j + k + 0];
            s1 += yrow[33 * j + k + 1];
            s2 += yrow[33 * j + k + 2];
            s3 += yrow[33 * j + k + 3];
        }
        if (half == 0) {
            yb[t0 + j] = (s0 + s1) + (s2 + s3) + bo;
        }
        __builtin_amdgcn_wave_barrier();   // next chunk's stash must not pass reads
    }

    if (half == 0) {
        out[(size_t)BB * TT + b * H + j] = h;   // h_n
    }
}

extern "C" void kernel_launch(void* const* d_in, const int* in_sizes, int n_in,
                              void* d_out, int out_size, void* d_ws, size_t ws_size,
                              hipStream_t stream) {
    const float* x     = (const float*)d_in[0];
    const float* h0    = (const float*)d_in[1];
    const float* W_ih  = (const float*)d_in[2];
    const float* W_hh  = (const float*)d_in[3];
    const float* b_ih  = (const float*)d_in[4];
    const float* b_hh  = (const float*)d_in[5];
    const float* W_out = (const float*)d_in[6];
    const float* b_out = (const float*)d_in[7];
    float* out = (float*)d_out;

    dim3 grid(BB / 4);   // 512 blocks, 4 waves (batches) each
    dim3 block(256);
    gru_fused<<<grid, block, 0, stream>>>(x, h0, W_ih, W_hh, b_ih, b_hh,
                                          W_out, b_out, out);
}

// Round 10
// 312.100 us; speedup vs baseline: 1.1476x; 1.1476x over previous
//
#include <hip/hip_runtime.h>

// GRU: H=32, I=1, B=2048, T=1024, fused output Linear(32,1).
// v10 = v9 + mandatory TRANS wait states. v9's absmax=2.57 failure and v8's
// marginal 0.0078 (4x v7's 0.00195 on identical math) are both explained by
// CDNA's manually-inserted-wait-state rule: a VALU TRANS op (v_exp_f32,
// v_rcp_f32, ...) followed by a dependent VALU read is NOT interlocked.
// Every trans->consumer edge now has >=3 cycles of independent work / s_nop.
// Structure (v9): half-wave per batch, FULL K per lane (f16 weights, 48
// dwords), 2 batches/wave, 1024 waves = 1/SIMD. One LDS round trip per step
// (h publish b16 + 4x broadcast ds_read_b128), no bpermute, 48 dot2/step.

constexpr int H  = 32;
constexpr int TT = 1024;
constexpr int BB = 2048;

typedef _Float16 hf2 __attribute__((ext_vector_type(2)));

__device__ __forceinline__ unsigned pack2(float a, float b) {
    hf2 t; t.x = (_Float16)a; t.y = (_Float16)b;
    return __builtin_bit_cast(unsigned, t);
}

__global__ __launch_bounds__(256, 1)
void gru_fused(const float* __restrict__ x,      // [B,T]
               const float* __restrict__ h0,     // [1,B,H]
               const float* __restrict__ W_ih,   // [3H,1]
               const float* __restrict__ W_hh,   // [3H,H]
               const float* __restrict__ b_ih,   // [3H]
               const float* __restrict__ b_hh,   // [3H]
               const float* __restrict__ W_out,  // [1,H]
               const float* __restrict__ b_out,  // [1]
               float* __restrict__ out)          // y[B,T] ++ h_n[B,H]
{
    __shared__ __align__(16) _Float16 hbuf[4][64];   // [wave][half*32+unit]
    __shared__ float xstage[4][64];                  // [wave][half*32+j]
    __shared__ float ybuf[4][2][36 * 32];            // [wave][half][36*s + j]

    const int tid  = threadIdx.x;
    const int w    = tid >> 6;
    const int lane = tid & 63;
    const int half = lane >> 5;
    const int j    = lane & 31;
    const int gw   = (blockIdx.x << 2) | w;   // global wave id, 0..1023
    const int b    = (gw << 1) | half;        // this lane's batch

    const float NL2E = -1.44269504f;   // -log2(e): folded into r,z weights
    const float P2L2 =  2.88539008f;   //  2*log2(e): folded into n weights

    // --- weights: FULL rows {j, H+j, 2H+j} of W_hh, pre-scaled, f16 pairs ---
    const float* Wrp = &W_hh[(0 * H + j) * H];
    const float* Wzp = &W_hh[(1 * H + j) * H];
    const float* Wnp = &W_hh[(2 * H + j) * H];
    unsigned wr[16], wz[16], wn[16];
#pragma unroll
    for (int k = 0; k < 16; ++k) {
        wr[k] = pack2(Wrp[2 * k] * NL2E, Wrp[2 * k + 1] * NL2E);
        wz[k] = pack2(Wzp[2 * k] * NL2E, Wzp[2 * k + 1] * NL2E);
        wn[k] = pack2(Wnp[2 * k] * P2L2, Wnp[2 * k + 1] * P2L2);
    }
    // full biases / input weights (no half-zeroing: full K per lane)
    const float wir = W_ih[j] * NL2E;
    const float wiz = W_ih[H + j] * NL2E;
    const float br  = (b_ih[j] + b_hh[j]) * NL2E;
    const float bz  = (b_ih[H + j] + b_hh[H + j]) * NL2E;
    const float bhn = b_hh[2 * H + j] * P2L2;
    const float win = W_ih[2 * H + j] * P2L2;
    const float bin = b_ih[2 * H + j] * P2L2;
    const float wo  = W_out[j];
    const float bo  = b_out[0];

    float h = h0[b * H + j];

    const float* xb = x + (size_t)b * TT;     // per-lane batch
    float*       yb = out + (size_t)b * TT;

    // LDS raw addresses
    const unsigned ha = (unsigned)(size_t)&hbuf[w][half * 32 + j];   // h publish (b16)
    const unsigned hr = (unsigned)(size_t)&hbuf[w][half * 32];       // own batch h, 64B
    const unsigned xw = (unsigned)(size_t)&xstage[w][half * 32 + j]; // x stage write
    const unsigned xa = (unsigned)(size_t)&xstage[w][half * 32];     // x read base (+4/step)
    const unsigned ya = (unsigned)(size_t)&ybuf[w][half][j];         // y stash base (+144/step)
    const float* yr = &ybuf[w][half][0];

#pragma unroll 1
    for (int t0 = 0; t0 < TT; t0 += 32) {
        const float xv = xb[t0 + j];   // lane j: x[t0+j] of its own batch

        asm volatile(
            "s_mov_b32 s20, 0\n\t"
            "v_mov_b32 v82, %[ya]\n\t"
            "v_mov_b32 v83, %[xa]\n\t"
            "ds_write_b32 %[xw], %[xv]\n\t"            // stage x chunk (in-order vs reads)
            "L_gru_%=:\n\t"
            "v_cvt_f16_f32 v33, %[h]\n\t"
            "ds_write_b16 %[ha], v33\n\t"
            "ds_read_b128 v[36:39], %[hr]\n\t"
            "ds_read_b128 v[40:43], %[hr] offset:16\n\t"
            "ds_read_b128 v[44:47], %[hr] offset:32\n\t"
            "ds_read_b128 v[48:51], %[hr] offset:48\n\t"
            "ds_read_b32 v80, v83\n\t"                 // x_t (uniform per half)
            "s_waitcnt lgkmcnt(0)\n\t"
            "v_dot2_f32_f16 v68, %[r0], v36, %[br]\n\t"
            "v_dot2_f32_f16 v69, %[z0], v36, %[bz]\n\t"
            "v_dot2_f32_f16 v70, %[n0], v36, %[bn]\n\t"
            "v_dot2_f32_f16 v68, %[r1], v37, v68\n\t"
            "v_dot2_f32_f16 v69, %[z1], v37, v69\n\t"
            "v_dot2_f32_f16 v70, %[n1], v37, v70\n\t"
            "v_dot2_f32_f16 v68, %[r2], v38, v68\n\t"
            "v_dot2_f32_f16 v69, %[z2], v38, v69\n\t"
            "v_dot2_f32_f16 v70, %[n2], v38, v70\n\t"
            "v_dot2_f32_f16 v68, %[r3], v39, v68\n\t"
            "v_dot2_f32_f16 v69, %[z3], v39, v69\n\t"
            "v_dot2_f32_f16 v70, %[n3], v39, v70\n\t"
            "v_dot2_f32_f16 v68, %[r4], v40, v68\n\t"
            "v_dot2_f32_f16 v69, %[z4], v40, v69\n\t"
            "v_dot2_f32_f16 v70, %[n4], v40, v70\n\t"
            "v_dot2_f32_f16 v68, %[r5], v41, v68\n\t"
            "v_dot2_f32_f16 v69, %[z5], v41, v69\n\t"
            "v_dot2_f32_f16 v70, %[n5], v41, v70\n\t"
            "v_dot2_f32_f16 v68, %[r6], v42, v68\n\t"
            "v_dot2_f32_f16 v69, %[z6], v42, v69\n\t"
            "v_dot2_f32_f16 v70, %[n6], v42, v70\n\t"
            "v_dot2_f32_f16 v68, %[r7], v43, v68\n\t"
            "v_dot2_f32_f16 v69, %[z7], v43, v69\n\t"
            "v_dot2_f32_f16 v70, %[n7], v43, v70\n\t"
            "v_dot2_f32_f16 v68, %[r8], v44, v68\n\t"
            "v_dot2_f32_f16 v69, %[z8], v44, v69\n\t"
            "v_dot2_f32_f16 v70, %[n8], v44, v70\n\t"
            "v_dot2_f32_f16 v68, %[r9], v45, v68\n\t"
            "v_dot2_f32_f16 v69, %[z9], v45, v69\n\t"
            "v_dot2_f32_f16 v70, %[n9], v45, v70\n\t"
            "v_dot2_f32_f16 v68, %[r10], v46, v68\n\t"
            "v_dot2_f32_f16 v69, %[z10], v46, v69\n\t"
            "v_dot2_f32_f16 v70, %[n10], v46, v70\n\t"
            "v_dot2_f32_f16 v68, %[r11], v47, v68\n\t"
            "v_dot2_f32_f16 v69, %[z11], v47, v69\n\t"
            "v_dot2_f32_f16 v70, %[n11], v47, v70\n\t"
            "v_dot2_f32_f16 v68, %[r12], v48, v68\n\t"
            "v_dot2_f32_f16 v69, %[z12], v48, v69\n\t"
            "v_dot2_f32_f16 v70, %[n12], v48, v70\n\t"
            "v_dot2_f32_f16 v68, %[r13], v49, v68\n\t"
            "v_dot2_f32_f16 v69, %[z13], v49, v69\n\t"
            "v_dot2_f32_f16 v70, %[n13], v49, v70\n\t"
            "v_dot2_f32_f16 v68, %[r14], v50, v68\n\t"
            "v_dot2_f32_f16 v69, %[z14], v50, v69\n\t"
            "v_dot2_f32_f16 v70, %[n14], v50, v70\n\t"
            "v_dot2_f32_f16 v68, %[r15], v51, v68\n\t"
            "v_dot2_f32_f16 v69, %[z15], v51, v69\n\t"
            "v_dot2_f32_f16 v70, %[n15], v51, v70\n\t"
            "v_fmac_f32 v68, v80, %[wir]\n\t"
            "v_fmac_f32 v69, v80, %[wiz]\n\t"
            // ---- gate tail with mandatory TRANS wait states ----
            "v_exp_f32 v71, v68\n\t"
            "v_exp_f32 v72, v69\n\t"
            "v_fma_f32 v74, v80, %[wi], %[bi]\n\t"   // independent filler
            "s_nop 2\n\t"
            "v_add_f32 v71, 1.0, v71\n\t"
            "v_add_f32 v72, 1.0, v72\n\t"
            "v_rcp_f32 v71, v71\n\t"
            "v_rcp_f32 v72, v72\n\t"
            "s_nop 2\n\t"
            "v_fmac_f32 v74, v71, v70\n\t"
            "v_exp_f32 v75, v74\n\t"
            "s_nop 2\n\t"
            "v_add_f32 v75, 1.0, v75\n\t"
            "v_rcp_f32 v75, v75\n\t"
            "s_nop 2\n\t"
            "v_fma_f32 v76, -2.0, v75, 1.0\n\t"
            "v_sub_f32 v77, %[h], v76\n\t"
            "v_fma_f32 %[h], v72, v77, v76\n\t"
            "v_mul_f32 v78, %[wo], %[h]\n\t"
            "ds_write_b32 v82, v78\n\t"
            "v_add_u32 v82, 144, v82\n\t"
            "v_add_u32 v83, 4, v83\n\t"
            "s_add_i32 s20, s20, 1\n\t"
            "s_cmp_lt_u32 s20, 32\n\t"
            "s_cbranch_scc1 L_gru_%=\n\t"
            "s_waitcnt lgkmcnt(0)"
            : [h]"+v"(h)
            : [xv]"v"(xv), [ha]"v"(ha), [hr]"v"(hr), [xw]"v"(xw), [xa]"v"(xa),
              [ya]"v"(ya),
              [wir]"v"(wir), [wiz]"v"(wiz), [wi]"v"(win), [bi]"v"(bin),
              [wo]"v"(wo), [br]"v"(br), [bz]"v"(bz), [bn]"v"(bhn),
              [r0]"v"(wr[0]), [r1]"v"(wr[1]), [r2]"v"(wr[2]), [r3]"v"(wr[3]),
              [r4]"v"(wr[4]), [r5]"v"(wr[5]), [r6]"v"(wr[6]), [r7]"v"(wr[7]),
              [r8]"v"(wr[8]), [r9]"v"(wr[9]), [r10]"v"(wr[10]), [r11]"v"(wr[11]),
              [r12]"v"(wr[12]), [r13]"v"(wr[13]), [r14]"v"(wr[14]), [r15]"v"(wr[15]),
              [z0]"v"(wz[0]), [z1]"v"(wz[1]), [z2]"v"(wz[2]), [z3]"v"(wz[3]),
              [z4]"v"(wz[4]), [z5]"v"(wz[5]), [z6]"v"(wz[6]), [z7]"v"(wz[7]),
              [z8]"v"(wz[8]), [z9]"v"(wz[9]), [z10]"v"(wz[10]), [z11]"v"(wz[11]),
              [z12]"v"(wz[12]), [z13]"v"(wz[13]), [z14]"v"(wz[14]), [z15]"v"(wz[15]),
              [n0]"v"(wn[0]), [n1]"v"(wn[1]), [n2]"v"(wn[2]), [n3]"v"(wn[3]),
              [n4]"v"(wn[4]), [n5]"v"(wn[5]), [n6]"v"(wn[6]), [n7]"v"(wn[7]),
              [n8]"v"(wn[8]), [n9]"v"(wn[9]), [n10]"v"(wn[10]), [n11]"v"(wn[11]),
              [n12]"v"(wn[12]), [n13]"v"(wn[13]), [n14]"v"(wn[14]), [n15]"v"(wn[15])
            : "memory", "scc", "s20",
              "v33", "v36", "v37", "v38", "v39", "v40", "v41", "v42", "v43",
              "v44", "v45", "v46", "v47", "v48", "v49", "v50", "v51",
              "v68", "v69", "v70", "v71", "v72", "v74", "v75", "v76", "v77",
              "v78", "v80", "v82", "v83");

        // amortized y reduction: lane (half,j) sums its own batch's row j
        float s0 = 0.0f, s1 = 0.0f, s2 = 0.0f, s3 = 0.0f;
#pragma unroll
        for (int k = 0; k < 32; k += 4) {
            s0 += yr[36 * j + k + 0];
            s1 += yr[36 * j + k + 1];
            s2 += yr[36 * j + k + 2];
            s3 += yr[36 * j + k + 3];
        }
        yb[t0 + j] = (s0 + s1) + (s2 + s3) + bo;   // all 64 lanes: own batch
        __builtin_amdgcn_wave_barrier();
    }

    out[(size_t)BB * TT + b * H + j] = h;          // h_n, all 64 lanes
}

extern "C" void kernel_launch(void* const* d_in, const int* in_sizes, int n_in,
                              void* d_out, int out_size, void* d_ws, size_t ws_size,
                              hipStream_t stream) {
    const float* x     = (const float*)d_in[0];
    const float* h0    = (const float*)d_in[1];
    const float* W_ih  = (const float*)d_in[2];
    const float* W_hh  = (const float*)d_in[3];
    const float* b_ih  = (const float*)d_in[4];
    const float* b_hh  = (const float*)d_in[5];
    const float* W_out = (const float*)d_in[6];
    const float* b_out = (const float*)d_in[7];
    float* out = (float*)d_out;

    dim3 grid(BB / 8);   // 256 blocks: 4 waves x 2 batches each
    dim3 block(256);
    gru_fused<<<grid, block, 0, stream>>>(x, h0, W_ih, W_hh, b_ih, b_hh,
                                          W_out, b_out, out);
}